// Round 1
// baseline (208.282 us; speedup 1.0000x reference)
//
#include <hip/hip_runtime.h>
#include <math.h>

#define N_NODES 50000
#define N_EDGES 800000
#define IN_DIM 128
#define N_HEADS 4
#define OUT_DIM 32
#define PROJ_DIM 128   // N_HEADS * OUT_DIM

// Kernel A: proj = X @ W (50000x128 @ 128x128) fused with per-(node,head)
// score precompute: s_src[n,h] = dot(proj[n,h,:], a_src), s_tgt likewise.
// Block = 256 threads handles 16 rows. c = tid & 127 (output col),
// rg = tid >> 7 selects row-subgroup of 8. Head groups of 32 cols align
// with lane%32 so width-32 shuffle reduction produces the dot products.
__global__ __launch_bounds__(256) void proj_kernel(
    const float* __restrict__ X, const float* __restrict__ W,
    const float* __restrict__ att,
    float* __restrict__ proj, float* __restrict__ s_src, float* __restrict__ s_tgt)
{
    __shared__ float xs[16][IN_DIM];
    const int tid = threadIdx.x;
    const int rbase = blockIdx.x * 16;

    // stage 16 rows of X into LDS (2048 floats, 8 per thread, coalesced)
    for (int i = tid; i < 16 * IN_DIM; i += 256) {
        int r = i >> 7;          // i / 128
        int k = i & 127;
        int gr = rbase + r;
        xs[r][k] = (gr < N_NODES) ? X[(long long)gr * IN_DIM + k] : 0.0f;
    }
    __syncthreads();

    const int c = tid & 127;
    const int rg = tid >> 7;     // 0 or 1

    float acc[8];
#pragma unroll
    for (int i = 0; i < 8; ++i) acc[i] = 0.0f;

    for (int k = 0; k < IN_DIM; ++k) {
        float w = W[k * PROJ_DIM + c];   // coalesced across lanes, L2-resident
#pragma unroll
        for (int i = 0; i < 8; ++i)
            acc[i] = fmaf(xs[rg * 8 + i][k], w, acc[i]);  // LDS broadcast
    }

    const int d = c & 31;
    const int h = c >> 5;
    const float a_s = att[d];
    const float a_t = att[OUT_DIM + d];

#pragma unroll
    for (int i = 0; i < 8; ++i) {
        int gr = rbase + rg * 8 + i;
        float v = acc[i];
        if (gr < N_NODES) proj[(long long)gr * PROJ_DIM + c] = v;
        // width-32 reduction over d for the two score dot-products
        float vs = v * a_s;
        float vt = v * a_t;
#pragma unroll
        for (int off = 16; off > 0; off >>= 1) {
            vs += __shfl_down(vs, off, 32);
            vt += __shfl_down(vt, off, 32);
        }
        if (d == 0 && gr < N_NODES) {
            s_src[gr * N_HEADS + h] = vs;
            s_tgt[gr * N_HEADS + h] = vt;
        }
    }
}

// Kernel B: per-edge attention + scatter. One thread per (edge, d):
// 32 consecutive lanes share an edge -> score loads broadcast, proj
// gathers coalesce to 128B per (edge,head), atomics coalesce to 128B.
__global__ __launch_bounds__(256) void edge_kernel(
    const int* __restrict__ ei,
    const float* __restrict__ proj,
    const float* __restrict__ s_src, const float* __restrict__ s_tgt,
    float* __restrict__ out)
{
    long long gidx = (long long)blockIdx.x * 256 + threadIdx.x;
    long long e = gidx >> 5;
    int d = (int)(gidx & 31);
    if (e >= N_EDGES) return;

    int src = ei[e];
    int tgt = ei[N_EDGES + e];

    float sc[4];
    float m = -1e30f;
#pragma unroll
    for (int h = 0; h < N_HEADS; ++h) {
        float s = s_src[src * N_HEADS + h] + s_tgt[tgt * N_HEADS + h];
        s = (s > 0.0f) ? s : 0.01f * s;     // leaky_relu(0.01)
        sc[h] = s;
        m = fmaxf(m, s);
    }
    float sum = 0.0f;
#pragma unroll
    for (int h = 0; h < N_HEADS; ++h) {
        sc[h] = __expf(sc[h] - m);
        sum += sc[h];
    }
    float inv = 0.25f / sum;   // softmax normalize * mean over 4 heads

    const float* pt = proj + (long long)tgt * PROJ_DIM + d;
    float w = 0.0f;
#pragma unroll
    for (int h = 0; h < N_HEADS; ++h)
        w = fmaf(sc[h], pt[h * OUT_DIM], w);

    atomicAdd(&out[src * OUT_DIM + d], w * inv);
}

extern "C" void kernel_launch(void* const* d_in, const int* in_sizes, int n_in,
                              void* d_out, int out_size, void* d_ws, size_t ws_size,
                              hipStream_t stream) {
    const float* X   = (const float*)d_in[0];
    const int*   ei  = (const int*)d_in[1];
    const float* W   = (const float*)d_in[2];
    const float* att = (const float*)d_in[3];
    float* out = (float*)d_out;

    float* proj  = (float*)d_ws;                       // 50000*128 floats = 25.6 MB
    float* s_src = proj + (size_t)N_NODES * PROJ_DIM;  // 50000*4
    float* s_tgt = s_src + (size_t)N_NODES * N_HEADS;  // 50000*4

    hipMemsetAsync(d_out, 0, (size_t)out_size * sizeof(float), stream);

    proj_kernel<<<(N_NODES + 15) / 16, 256, 0, stream>>>(X, W, att, proj, s_src, s_tgt);

    long long threads = (long long)N_EDGES * 32;
    edge_kernel<<<(int)((threads + 255) / 256), 256, 0, stream>>>(ei, proj, s_src, s_tgt, out);
}

// Round 3
// 200.080 us; speedup vs baseline: 1.0410x; 1.0410x over previous
//
#include <hip/hip_runtime.h>
#include <math.h>

#define N_NODES 50000
#define N_EDGES 800000
#define IN_DIM 128
#define N_HEADS 4
#define OUT_DIM 32
#define PROJ_DIM 128   // N_HEADS * OUT_DIM

// fp32 -> bf16 bits with round-to-nearest-even
__device__ __forceinline__ ushort f32_to_bf16(float f) {
    unsigned u = __float_as_uint(f);
    unsigned r = u + 0x7fffu + ((u >> 16) & 1u);
    return (ushort)(r >> 16);
}

// ---------------------------------------------------------------------------
// Kernel A: proj = X @ W (50000x128 @ 128x128), register-blocked.
//   Block = 256 threads, tile = 64 rows x 128 cols.
//   Thread: d = tid&31 (dim index), rg = tid>>5 (row group of 8).
//   Each thread computes 8 rows x 4 cols, cols = {h*32+d : h=0..3}.
//   LDS X reads are float4 (ds_read_b128, wave-uniform broadcast), so the
//   inner loop is FMA-bound (128 FMA per 8 LDS reads per 4-k step).
//   Epilogue: store projT[row][d][h] as bf16 ushort4 (8B coalesced store),
//   and shuffle-reduce (width 32 over d) the two score dot products in fp32.
// ---------------------------------------------------------------------------
__global__ __launch_bounds__(256) void proj_kernel(
    const float* __restrict__ X, const float* __restrict__ W,
    const float* __restrict__ att,
    ushort* __restrict__ projT, float* __restrict__ s_src, float* __restrict__ s_tgt)
{
    __shared__ float xs[64][IN_DIM];   // 32 KB

    const int tid = threadIdx.x;
    const int rbase = blockIdx.x * 64;

    // stage 64 rows of X as float4 (2048 float4 / 256 threads = 8 each)
    {
        const float4* X4 = (const float4*)X;
        float4* xs4 = (float4*)&xs[0][0];
        for (int i = tid; i < 64 * (IN_DIM / 4); i += 256) {
            int r = i >> 5;                 // i / 32 float4s per row
            int gr = rbase + r;
            float4 v = make_float4(0.f, 0.f, 0.f, 0.f);
            if (gr < N_NODES) v = X4[(long long)rbase * 32 + i];
            xs4[i] = v;
        }
    }
    __syncthreads();

    const int d  = tid & 31;
    const int rg = tid >> 5;           // 0..7

    float acc[8][4];
#pragma unroll
    for (int i = 0; i < 8; ++i)
#pragma unroll
        for (int h = 0; h < 4; ++h) acc[i][h] = 0.0f;

    for (int k = 0; k < IN_DIM; k += 4) {
        // W values for this 4-k slab: W[k+kk][h*32+d], coalesced across lanes
        float wv[4][4];
#pragma unroll
        for (int kk = 0; kk < 4; ++kk)
#pragma unroll
            for (int h = 0; h < 4; ++h)
                wv[kk][h] = W[(k + kk) * PROJ_DIM + h * OUT_DIM + d];

#pragma unroll
        for (int i = 0; i < 8; ++i) {
            float4 xv = *(const float4*)&xs[rg * 8 + i][k];   // ds_read_b128 broadcast
#pragma unroll
            for (int h = 0; h < 4; ++h) {
                acc[i][h] = fmaf(xv.x, wv[0][h], acc[i][h]);
                acc[i][h] = fmaf(xv.y, wv[1][h], acc[i][h]);
                acc[i][h] = fmaf(xv.z, wv[2][h], acc[i][h]);
                acc[i][h] = fmaf(xv.w, wv[3][h], acc[i][h]);
            }
        }
    }

    const float a_s = att[d];
    const float a_t = att[OUT_DIM + d];

#pragma unroll
    for (int i = 0; i < 8; ++i) {
        int gr = rbase + rg * 8 + i;

        // pack 4 head values (bf16) -> one 8B store: projT[gr*128 + d*4 + h]
        if (gr < N_NODES) {
            ushort4 pv;
            pv.x = f32_to_bf16(acc[i][0]);
            pv.y = f32_to_bf16(acc[i][1]);
            pv.z = f32_to_bf16(acc[i][2]);
            pv.w = f32_to_bf16(acc[i][3]);
            *(ushort4*)&projT[(long long)gr * PROJ_DIM + d * 4] = pv;
        }

        // score partials, reduced over d (width-32, the two wave halves are
        // independent row groups so width-32 shuffles stay within a group)
        float vs[4], vt[4];
#pragma unroll
        for (int h = 0; h < 4; ++h) {
            vs[h] = acc[i][h] * a_s;
            vt[h] = acc[i][h] * a_t;
        }
#pragma unroll
        for (int off = 16; off > 0; off >>= 1) {
#pragma unroll
            for (int h = 0; h < 4; ++h) {
                vs[h] += __shfl_down(vs[h], off, 32);
                vt[h] += __shfl_down(vt[h], off, 32);
            }
        }
        if (d == 0 && gr < N_NODES) {
            *(float4*)&s_src[gr * N_HEADS] = make_float4(vs[0], vs[1], vs[2], vs[3]);
            *(float4*)&s_tgt[gr * N_HEADS] = make_float4(vt[0], vt[1], vt[2], vt[3]);
        }
    }
}

// ---------------------------------------------------------------------------
// Kernel B: per-edge attention + scatter. 32 consecutive lanes per edge,
// lane = dim d. Scores load as broadcast float4; proj gather is ONE ushort4
// (4 bf16, one per head) per lane = 256B coalesced per edge.
// ---------------------------------------------------------------------------
__global__ __launch_bounds__(256) void edge_kernel(
    const int* __restrict__ ei,
    const ushort* __restrict__ projT,
    const float* __restrict__ s_src, const float* __restrict__ s_tgt,
    float* __restrict__ out)
{
    long long gidx = (long long)blockIdx.x * 256 + threadIdx.x;
    long long e = gidx >> 5;
    int d = (int)(gidx & 31);
    if (e >= N_EDGES) return;

    int src = ei[e];
    int tgt = ei[N_EDGES + e];

    float4 ss = *(const float4*)&s_src[src * N_HEADS];
    float4 st = *(const float4*)&s_tgt[tgt * N_HEADS];

    float sc[4] = { ss.x + st.x, ss.y + st.y, ss.z + st.z, ss.w + st.w };
    float m = -1e30f;
#pragma unroll
    for (int h = 0; h < 4; ++h) {
        sc[h] = (sc[h] > 0.0f) ? sc[h] : 0.01f * sc[h];   // leaky_relu(0.01)
        m = fmaxf(m, sc[h]);
    }
    float sum = 0.0f;
#pragma unroll
    for (int h = 0; h < 4; ++h) {
        sc[h] = __expf(sc[h] - m);
        sum += sc[h];
    }
    float inv = 0.25f / sum;   // softmax normalize * mean over heads

    ushort4 pv = *(const ushort4*)&projT[(long long)tgt * PROJ_DIM + d * 4];
    float p0 = __uint_as_float((unsigned)pv.x << 16);
    float p1 = __uint_as_float((unsigned)pv.y << 16);
    float p2 = __uint_as_float((unsigned)pv.z << 16);
    float p3 = __uint_as_float((unsigned)pv.w << 16);

    float w = sc[0] * p0;
    w = fmaf(sc[1], p1, w);
    w = fmaf(sc[2], p2, w);
    w = fmaf(sc[3], p3, w);

    atomicAdd(&out[src * OUT_DIM + d], w * inv);
}

extern "C" void kernel_launch(void* const* d_in, const int* in_sizes, int n_in,
                              void* d_out, int out_size, void* d_ws, size_t ws_size,
                              hipStream_t stream) {
    const float* X   = (const float*)d_in[0];
    const int*   ei  = (const int*)d_in[1];
    const float* W   = (const float*)d_in[2];
    const float* att = (const float*)d_in[3];
    float* out = (float*)d_out;

    ushort* projT = (ushort*)d_ws;                                   // 12.8 MB bf16
    float* s_src  = (float*)(projT + (size_t)N_NODES * PROJ_DIM);    // 50000*4 f32
    float* s_tgt  = s_src + (size_t)N_NODES * N_HEADS;

    (void)hipMemsetAsync(d_out, 0, (size_t)out_size * sizeof(float), stream);

    proj_kernel<<<(N_NODES + 63) / 64, 256, 0, stream>>>(X, W, att, projT, s_src, s_tgt);

    long long threads = (long long)N_EDGES * 32;
    edge_kernel<<<(int)((threads + 255) / 256), 256, 0, stream>>>(ei, projT, s_src, s_tgt, out);
}